// Round 11
// baseline (307.327 us; speedup 1.0000x reference)
//
#include <hip/hip_runtime.h>
#include <cmath>

// ---------------------------------------------------------------- types
typedef __bf16 bf16x8 __attribute__((ext_vector_type(8)));
typedef __bf16 bf16x4 __attribute__((ext_vector_type(4)));
typedef float  floatx4 __attribute__((ext_vector_type(4)));

#define LN_EPS 1e-5f
#define INV_TEMP 0.125f   // 1/sqrt(64)

// B=32 S=512 D=512 H=8 DK=DV=64 DFF=2048, M = B*S = 16384
static const int Mrows = 16384;

__device__ __forceinline__ void gload_lds16(const void* g, void* l) {
  __builtin_amdgcn_global_load_lds(
      (const __attribute__((address_space(1))) void*)g,
      (__attribute__((address_space(3))) void*)l, 16, 0, 0);
}

// ---------------------------------------------------------------- fused prep: x->bf16 + 6 weight transposes
__global__ __launch_bounds__(256) void prep_kernel(const float* __restrict__ x, __bf16* __restrict__ xb,
                                                   const float* __restrict__ wq, const float* __restrict__ wk,
                                                   const float* __restrict__ wv, const float* __restrict__ wo,
                                                   const float* __restrict__ wff1, const float* __restrict__ wff2,
                                                   __bf16* __restrict__ tq, __bf16* __restrict__ tk,
                                                   __bf16* __restrict__ tv, __bf16* __restrict__ to_,
                                                   __bf16* __restrict__ tff1, __bf16* __restrict__ tff2) {
  const int bid = blockIdx.x, tid = threadIdx.x;
  if (bid < 8192) {
    int i = bid * 256 + tid;
    float4 v = ((const float4*)x)[i];
    __bf16* d = xb + i * 4;
    d[0] = (__bf16)v.x; d[1] = (__bf16)v.y; d[2] = (__bf16)v.z; d[3] = (__bf16)v.w;
    return;
  }
  __shared__ __bf16 til[64][72];
  int t = bid - 8192;
  const float* src; __bf16* dst; int R, C, bx, by;
  if (t < 256) {
    int w = t >> 6, tt = t & 63;
    const float* srcs[4] = {wq, wk, wv, wo};
    __bf16* dsts[4] = {tq, tk, tv, to_};
    src = srcs[w]; dst = dsts[w]; R = 512; C = 512; bx = tt & 7; by = tt >> 3;
  } else if (t < 512) {
    int tt = t - 256;
    src = wff1; dst = tff1; R = 512; C = 2048; bx = tt & 31; by = tt >> 5;
  } else {
    int tt = t - 512;
    src = wff2; dst = tff2; R = 2048; C = 512; bx = tt & 7; by = tt >> 3;
  }
  const float* s = src + (size_t)(by * 64) * C + bx * 64;
  int r = tid >> 4, c4 = (tid & 15) * 4;
  for (int p = 0; p < 4; ++p) {
    int rr = r + p * 16;
    float4 v = *(const float4*)(s + (size_t)rr * C + c4);
    til[c4 + 0][rr] = (__bf16)v.x;
    til[c4 + 1][rr] = (__bf16)v.y;
    til[c4 + 2][rr] = (__bf16)v.z;
    til[c4 + 3][rr] = (__bf16)v.w;
  }
  __syncthreads();
  __bf16* d = dst + (size_t)(bx * 64) * R + by * 64;
  int orow = tid >> 3, oc8 = (tid & 7) * 8;
  for (int p = 0; p < 2; ++p) {
    int rr = orow + p * 32;
    *(bf16x8*)(d + (size_t)rr * R + oc8) = *(const bf16x8*)(&til[rr][oc8]);
  }
}

// ---------------------------------------------------------------- 128x256 8-wave GEMM, 3-slot K-half ring
// R10 structure; CHANGE vs R10: the explicit lgkmcnt(0) between the ds_read
// burst and the MFMA burst is REMOVED. The reads are plain loads with true
// register deps into the MFMAs, so the compiler emits fine-grained COUNTED
// lgkmcnt waits (m97 asm) - MFMAs start while later reads are in flight,
// breaking the read-burst/MFMA-burst convoy that capped MfmaUtil at 30%.
// WAR on restaged slots still safe: every read has a consuming MFMA in the
// same phase, so all reads are retired before the wave passes the next
// barrier.
template <int EPI, int NBN, int NDIM, int KDIM, int NKS>
__global__ __launch_bounds__(512, 4) void gemm256(const __bf16* __restrict__ A,
                                                  const __bf16* __restrict__ Bt,
                                                  __bf16* __restrict__ Cv,
                                                  const float* __restrict__ bias,
                                                  float* __restrict__ norms,
                                                  __bf16* __restrict__ vtg) {
  __shared__ __align__(16) char smem[73728];
  const int tid = threadIdx.x;
  const int wave = tid >> 6, lane = tid & 63;
  const int l15 = lane & 15, quad = lane >> 4;
  const int wm = wave >> 2, wn = wave & 3;

  constexpr int NBM = Mrows / 128;          // 128
  constexpr int NBLK = NBM * NBN * NKS;
  constexpr int KS = KDIM / NKS;
  constexpr int NTH = KS / 32;

  int id = blockIdx.x;
  int t = (id & 7) * (NBLK >> 3) + (id >> 3);   // XCD-chunked bijective swizzle
  const int ks = t / (NBM * NBN);
  t -= ks * (NBM * NBN);
  const int nblk = t % NBN, mblk = t / NBN;
  const int m0 = mblk * 128, n0 = nblk * 256;
  const __bf16* Ab = A + (size_t)ks * KS;
  const __bf16* Bb = Bt + (size_t)ks * KS;
  __bf16* Cw = Cv + (size_t)ks * Mrows * NDIM;
  (void)bias;

  // stage mapping: 24 chunks (A 0-7, B 8-23), 3 per wave; pair-line layout.
  const int l3 = lane >> 3, s_ = lane & 7;
  const int rl = l3 * 2 + (s_ >> 2);
  const int ksw = (s_ & 3) ^ (l3 & 3);
  const __bf16* sb[3];
  int ldo[3];
#pragma unroll
  for (int j = 0; j < 3; ++j) {
    int c = wave * 3 + j;
    int isB = c >= 8 ? 1 : 0;
    int cc = c - isB * 8;
    int row = cc * 16 + rl;
    sb[j] = (isB ? Bb + (size_t)(n0 + row) * KDIM
                 : Ab + (size_t)(m0 + row) * KDIM) + ksw * 8;
    ldo[j] = isB * 8192 + cc * 1024 + lane * 16;
  }

  const int lrt = (l15 >> 1) * 128 + (((l15 & 1) * 4 + (quad ^ ((l15 >> 1) & 3))) * 16);

  floatx4 zero = {0.f, 0.f, 0.f, 0.f};
  floatx4 acc[4][4];
#pragma unroll
  for (int i = 0; i < 4; ++i)
#pragma unroll
    for (int j = 0; j < 4; ++j) acc[i][j] = zero;

#define STAGEH(h, slotIdx)                                                   \
  {                                                                          \
    _Pragma("unroll") for (int j = 0; j < 3; ++j)                            \
        gload_lds16(sb[j] + (h) * 32, smem + (slotIdx) * 24576 + ldo[j]);    \
  }

#define READMFMA(slotIdx)                                                    \
  {                                                                          \
    const char* slotp = smem + (slotIdx) * 24576;                            \
    bf16x8 aF[4], bF[4];                                                     \
    _Pragma("unroll") for (int i = 0; i < 4; ++i)                            \
      aF[i] = *(const bf16x8*)(slotp + (wm * 4 + i) * 1024 + lrt);           \
    _Pragma("unroll") for (int j = 0; j < 4; ++j)                            \
      bF[j] = *(const bf16x8*)(slotp + 8192 + (wn * 4 + j) * 1024 + lrt);    \
    DOSTAGE_HOOK;                                                            \
    __builtin_amdgcn_s_setprio(1);                                           \
    _Pragma("unroll") for (int i = 0; i < 4; ++i)                            \
      _Pragma("unroll") for (int j = 0; j < 4; ++j)                          \
        acc[i][j] = __builtin_amdgcn_mfma_f32_16x16x32_bf16(aF[i], bF[j],    \
                                                            acc[i][j], 0, 0, 0); \
    __builtin_amdgcn_s_setprio(0);                                           \
  }

  STAGEH(0, 0);
  STAGEH(1, 1);

  int sl = 0;
  for (int h = 0; h < NTH - 1; ++h) {
    asm volatile("s_waitcnt vmcnt(3)" ::: "memory");
    __builtin_amdgcn_s_barrier();
    int st = (sl == 0) ? 2 : sl - 1;          // (sl+2)%3
    if (h < NTH - 2) {
#define DOSTAGE_HOOK STAGEH(h + 2, st)
      READMFMA(sl);
#undef DOSTAGE_HOOK
    } else {
#define DOSTAGE_HOOK
      READMFMA(sl);
#undef DOSTAGE_HOOK
    }
    sl = (sl == 2) ? 0 : sl + 1;
  }
  asm volatile("s_waitcnt vmcnt(0)" ::: "memory");
  __builtin_amdgcn_s_barrier();
#define DOSTAGE_HOOK
  READMFMA(sl);
#undef DOSTAGE_HOOK

#undef STAGEH
#undef READMFMA

  if (EPI == 4) {
    int head_global = (n0 + wn * 64) >> 6;
    int kind = head_global >> 3;
    if (kind < 2) {
      int h = head_global & 7;
#pragma unroll
      for (int ii = 0; ii < 4; ++ii)
#pragma unroll
        for (int r = 0; r < 4; ++r) {
          float sq = 0.f;
#pragma unroll
          for (int jj = 0; jj < 4; ++jj) {
            float v = acc[ii][jj][r];
            sq += v * v;
          }
          for (int m = 1; m < 16; m <<= 1) sq += __shfl_xor(sq, m, 64);
          if (l15 == 0) {
            int arow = m0 + wm * 64 + ii * 16 + quad * 4 + r;
            int bb = arow >> 9, ss = arow & 511;
            norms[kind * 131072 + ((bb << 3) + h) * 512 + ss] = rsqrtf(sq);
          }
        }
    } else {
      const int PADT = 72;
      __bf16* Ct = (__bf16*)smem;
      int bb = m0 >> 9, s0r = m0 & 511;
#pragma unroll
      for (int hh = 0; hh < 2; ++hh) {
        __builtin_amdgcn_s_barrier();
        if (wm == hh) {
#pragma unroll
          for (int ii = 0; ii < 4; ++ii)
#pragma unroll
            for (int jj = 0; jj < 4; ++jj) {
              bf16x4 pk;
#pragma unroll
              for (int r = 0; r < 4; ++r) pk[r] = (__bf16)acc[ii][jj][r];
              *(bf16x4*)(Ct + (wn * 64 + jj * 16 + l15) * PADT + ii * 16 + quad * 4) = pk;
            }
        }
        __builtin_amdgcn_s_barrier();
#pragma unroll
        for (int p = 0; p < 4; ++p) {
          int c = p * 64 + (tid >> 3);
          int s8 = (tid & 7) * 8;
          int h = ((n0 + c) >> 6) & 7, d = c & 63;
          *(bf16x8*)(vtg + ((size_t)(((bb << 3) + h) * 64 + d)) * 512 + s0r + hh * 64 + s8) =
              *(const bf16x8*)(Ct + c * PADT + s8);
        }
      }
      return;
    }
  }

  const int PADC = 264;
  __bf16* Cs = (__bf16*)smem;
  float bv[4];
  if (EPI == 2) {
#pragma unroll
    for (int j = 0; j < 4; ++j) bv[j] = bias[n0 + wn * 64 + j * 16 + l15];
  }
#pragma unroll
  for (int hh = 0; hh < 2; ++hh) {
    __builtin_amdgcn_s_barrier();
    if (wm == hh) {
#pragma unroll
      for (int i = 0; i < 4; ++i)
#pragma unroll
        for (int j = 0; j < 4; ++j)
#pragma unroll
          for (int r = 0; r < 4; ++r) {
            float v = acc[i][j][r];
            if (EPI == 2) {
              v += bv[j];
              v = v > 0.f ? v : 0.f;
            }
            Cs[(i * 16 + quad * 4 + r) * PADC + wn * 64 + j * 16 + l15] = (__bf16)v;
          }
    }
    __builtin_amdgcn_s_barrier();
#pragma unroll
    for (int p = 0; p < 4; ++p) {
      int rowl = p * 16 + (tid >> 5);
      int c8 = (tid & 31) * 8;
      *(bf16x8*)(Cw + (size_t)(m0 + hh * 64 + rowl) * NDIM + n0 + c8) =
          *(const bf16x8*)(Cs + rowl * PADC + c8);
    }
  }
}

// ---------------------------------------------------------------- attention (2-slot K/V ring, hoisted fragments)
// (unchanged from round 10 - passing)
__global__ __launch_bounds__(256) void attn_kernel(const __bf16* __restrict__ qkv,
                                                   const __bf16* __restrict__ vtg,
                                                   const float* __restrict__ norms,
                                                   __bf16* __restrict__ out) {
  __shared__ __align__(16) __bf16 KV[2][8192];   // [slot][K 8KB | V 8KB] = 32KB
  __shared__ __align__(16) __bf16 P2[4][16 * 72];
  const int tid = threadIdx.x, wave = tid >> 6, lane = tid & 63;
  const int l15 = lane & 15, quad = lane >> 4;
  const int bh = blockIdx.x & 255;
  const int qq = blockIdx.x >> 8;
  const int b = bh >> 3, h = bh & 7;
  const int qbase = qq * 128 + wave * 32;
  const int rs = lane >> 3;
  const int swz_st = ((lane & 7) ^ rs) * 8;
  const int s7 = l15 & 7;

  const __bf16* Qb = qkv + (size_t)(b * 512) * 1536 + h * 64;
  const __bf16* Kb = Qb + 512;
  const __bf16* Vtb = vtg + (size_t)bh * 32768;
  const float* nkinv = norms + 131072 + bh * 512;
  const float* nqinv = norms + bh * 512;
  __bf16* Pw = P2[wave];

  bf16x8 aq[2][2];
  float cq[2];
  for (int ch = 0; ch < 2; ++ch) {
    int qrow = qbase + ch * 16;
    aq[ch][0] = *(const bf16x8*)(Qb + (size_t)(qrow + l15) * 1536 + quad * 8);
    aq[ch][1] = *(const bf16x8*)(Qb + (size_t)(qrow + l15) * 1536 + 32 + quad * 8);
    cq[ch] = nqinv[qrow + l15] * INV_TEMP;
  }

  floatx4 zero = {0.f, 0.f, 0.f, 0.f};
  floatx4 o[2][4];
  float lsum[2] = {0.f, 0.f};
  for (int ch = 0; ch < 2; ++ch)
    for (int jd = 0; jd < 4; ++jd) o[ch][jd] = zero;

#define STAGEKV(kt, s)                                                        \
  {                                                                           \
    int s0q = (kt) * 64;                                                      \
    _Pragma("unroll") for (int c = 0; c < 4; ++c) {                           \
      int g = wave * 4 + c;                                                   \
      const __bf16* src;                                                      \
      __bf16* dst;                                                            \
      if (g < 8) {                                                            \
        int sk = g * 8 + rs;                                                  \
        src = Kb + (size_t)(s0q + sk) * 1536 + swz_st;                        \
        dst = KV[s] + g * 512;                                                \
      } else {                                                                \
        int g2 = g - 8;                                                       \
        int dd = g2 * 8 + rs;                                                 \
        src = Vtb + (size_t)dd * 512 + s0q + swz_st;                          \
        dst = KV[s] + 4096 + g2 * 512;                                        \
      }                                                                       \
      gload_lds16(src, dst + lane * 8);                                       \
    }                                                                         \
  }

  STAGEKV(0, 0);

  for (int kt = 0; kt < 8; ++kt) {
    int s0 = kt * 64;
    int sl = kt & 1;
    asm volatile("s_waitcnt vmcnt(0)" ::: "memory");
    __builtin_amdgcn_s_barrier();
    if (kt < 7) STAGEKV(kt + 1, sl ^ 1);
    const __bf16* Ks = KV[sl];
    const __bf16* Vs = KV[sl] + 4096;

    // nk once per kt (shared by both ch)
    floatx4 nk[4];
#pragma unroll
    for (int j = 0; j < 4; ++j)
      nk[j] = *(const floatx4*)(nkinv + s0 + j * 16 + quad * 4);

    // K fragments once (8 b128)
    bf16x8 kf[4][2];
#pragma unroll
    for (int j = 0; j < 4; ++j) {
      int r64 = (j * 16 + l15) * 64;
      kf[j][0] = *(const bf16x8*)(Ks + r64 + ((quad ^ s7) * 8));
      kf[j][1] = *(const bf16x8*)(Ks + r64 + (((4 + quad) ^ s7) * 8));
    }

    // S^T both ch: lane -> (sk = j*16+quad*4+r, q = l15)
    floatx4 z[2][4];
    __builtin_amdgcn_s_setprio(1);
#pragma unroll
    for (int ch = 0; ch < 2; ++ch)
#pragma unroll
      for (int j = 0; j < 4; ++j) {
        floatx4 zz = zero;
        zz = __builtin_amdgcn_mfma_f32_16x16x32_bf16(kf[j][0], aq[ch][0], zz, 0, 0, 0);
        zz = __builtin_amdgcn_mfma_f32_16x16x32_bf16(kf[j][1], aq[ch][1], zz, 0, 0, 0);
        z[ch][j] = zz;
      }
    __builtin_amdgcn_s_setprio(0);

    // V fragments once (8 b128)
    bf16x8 vf[4][2];
#pragma unroll
    for (int jd = 0; jd < 4; ++jd) {
      int r64 = (jd * 16 + l15) * 64;
      vf[jd][0] = *(const bf16x8*)(Vs + r64 + ((quad ^ s7) * 8));
      vf[jd][1] = *(const bf16x8*)(Vs + r64 + (((4 + quad) ^ s7) * 8));
    }

#pragma unroll
    for (int ch = 0; ch < 2; ++ch) {
      // softmax numerator + P write (per-wave P2, 8 b64 writes)
#pragma unroll
      for (int j = 0; j < 4; ++j) {
        bf16x4 pk;
#pragma unroll
        for (int r = 0; r < 4; ++r) {
          float p = __expf(z[ch][j][r] * cq[ch] * nk[j][r]);
          lsum[ch] += p;
          pk[r] = (__bf16)p;
        }
        *(bf16x4*)(Pw + l15 * 72 + j * 16 + quad * 4) = pk;
      }
      bf16x8 ap0 = *(const bf16x8*)(Pw + l15 * 72 + quad * 8);
      bf16x8 ap1 = *(const bf16x8*)(Pw + l15 * 72 + 32 + quad * 8);
      __builtin_amdgcn_s_setprio(1);
#pragma unroll
      for (int jd = 0; jd < 4; ++jd) {
        o[ch][jd] = __builtin_amdgcn_mfma_f32_16x16x32_bf16(vf[jd][0], ap0, o[ch][jd], 0, 0, 0);
        o[ch][jd] = __builtin_amdgcn_mfma_f32_16x16x32_bf16(vf[jd][1], ap1, o[ch][jd], 0, 0, 0);
      }
      __builtin_amdgcn_s_setprio(0);
    }
  }
#undef STAGEKV

  for (int ch = 0; ch < 2; ++ch) {
    float s = lsum[ch];
    s += __shfl_xor(s, 16, 64);
    s += __shfl_xor(s, 32, 64);
    float inv = __builtin_amdgcn_rcpf(s);
    int q = qbase + ch * 16 + l15;
    __bf16* op = out + (size_t)(b * 512 + q) * 512 + h * 64;
    for (int jd = 0; jd < 4; ++jd) {
      bf16x4 pk;
      for (int r = 0; r < 4; ++r) pk[r] = (__bf16)(o[ch][jd][r] * inv);
      *(bf16x4*)(op + jd * 16 + quad * 4) = pk;
    }
  }
}

// ---------------------------------------------------------------- residual + layernorm
template <bool X1BF, bool WF, bool WB, bool DUAL>
__global__ __launch_bounds__(256) void resid_ln(const float* __restrict__ X1f,
                                                const __bf16* __restrict__ X1b,
                                                const __bf16* __restrict__ X2,
                                                const __bf16* __restrict__ X2b,
                                                const float* __restrict__ bias,
                                                const float* __restrict__ g,
                                                const float* __restrict__ be,
                                                float* __restrict__ outf,
                                                __bf16* __restrict__ outb) {
  int row = blockIdx.x * 4 + (threadIdx.x >> 6);
  int lane = threadIdx.x & 63;
  float v[8];
  bf16x8 b8 = *(const bf16x8*)(X2 + (size_t)row * 512 + lane * 8);
  if (X1BF) {
    bf16x8 a = *(const bf16x8*)(X1b + (size_t)row * 512 + lane * 8);
    for (int i = 0; i < 8; ++i) v[i] = (float)a[i] + (float)b8[i];
  } else {
    const float4* r1 = (const float4*)(X1f + (size_t)row * 512);
    float4 a0 = r1[lane * 2], a1 = r1[lane * 2 + 1];
    v[0] = a0.x; v[1] = a0.y; v[2] = a0.z; v[3] = a0.w;
    v[4] = a1.x; v[5] = a1.y; v[6] = a1.z; v[7] = a1.w;
    for (int i = 0; i < 8; ++i) v[i] += (float)b8[i];
  }
  if (DUAL) {
    bf16x8 c8 = *(const bf16x8*)(X2b + (size_t)row * 512 + lane * 8);
    for (int i = 0; i < 8; ++i) v[i] += (float)c8[i];
  }
  if (bias) {
    const float* bp = bias + lane * 8;
    for (int i = 0; i < 8; ++i) v[i] += bp[i];
  }
  float s = 0.f, sq = 0.f;
  for (int i = 0; i < 8; ++i) {
    s += v[i];
    sq += v[i] * v[i];
  }
  for (int m = 1; m < 64; m <<= 1) {
    s += __shfl_xor(s, m, 64);
    sq += __shfl_xor(sq, m, 64);
  }
  float mean = s * (1.f / 512.f);
  float var = sq * (1.f / 512.f) - mean * mean;
  float rstd = rsqrtf(var + LN_EPS);
  const float* gp = g + lane * 8;
  const float* bp2 = be + lane * 8;
  float o[8];
  for (int i = 0; i < 8; ++i) o[i] = (v[i] - mean) * rstd * gp[i] + bp2[i];
  if (WF) {
    float4 w0 = {o[0], o[1], o[2], o[3]}, w1 = {o[4], o[5], o[6], o[7]};
    ((float4*)(outf + (size_t)row * 512))[lane * 2] = w0;
    ((float4*)(outf + (size_t)row * 512))[lane * 2 + 1] = w1;
  }
  if (WB) {
    __bf16 tmp[8];
    for (int i = 0; i < 8; ++i) tmp[i] = (__bf16)o[i];
    *(bf16x8*)(outb + (size_t)row * 512 + lane * 8) = *(bf16x8*)tmp;
  }
}

// ---------------------------------------------------------------- launcher
extern "C" void kernel_launch(void* const* d_in, const int* in_sizes, int n_in,
                              void* d_out, int out_size, void* d_ws, size_t ws_size,
                              hipStream_t stream) {
  const float* x     = (const float*)d_in[0];
  const float* w_q   = (const float*)d_in[1];
  const float* w_k   = (const float*)d_in[2];
  const float* w_v   = (const float*)d_in[3];
  const float* w_o   = (const float*)d_in[4];
  const float* w_ff1 = (const float*)d_in[5];
  const float* b_ff1 = (const float*)d_in[6];
  const float* w_ff2 = (const float*)d_in[7];
  const float* b_ff2 = (const float*)d_in[8];
  const float* g1    = (const float*)d_in[9];
  const float* b1    = (const float*)d_in[10];
  const float* g2    = (const float*)d_in[11];
  const float* b2    = (const float*)d_in[12];
  float* out = (float*)d_out;

  char* ws = (char*)d_ws;
  size_t off = 0;
  auto alloc = [&](size_t bytes) -> void* {
    void* p = ws + off;
    off += (bytes + 255) & ~(size_t)255;
    return p;
  };
  __bf16* xb     = (__bf16*)alloc((size_t)Mrows * 512 * 2);
  __bf16* wt_qkv = (__bf16*)alloc((size_t)1536 * 512 * 2);
  __bf16* wt_o   = (__bf16*)alloc((size_t)512 * 512 * 2);
  __bf16* wt_ff1 = (__bf16*)alloc((size_t)2048 * 512 * 2);
  __bf16* wt_ff2 = (__bf16*)alloc((size_t)512 * 2048 * 2);
  __bf16* qkv    = (__bf16*)alloc((size_t)Mrows * 1536 * 2);
  float*  norms  = (float*)alloc((size_t)262144 * 4);
  __bf16* attn   = (__bf16*)alloc((size_t)Mrows * 512 * 2);
  __bf16* projb  = (__bf16*)alloc((size_t)Mrows * 512 * 2);   // contiguous after attn
  __bf16* h1b    = (__bf16*)alloc((size_t)Mrows * 512 * 2);
  __bf16* mid    = (__bf16*)alloc((size_t)Mrows * 2048 * 2);
  __bf16* vtg    = mid;            // alias: vtg dead before w_o writes mid
  __bf16* wo_p   = mid;            // w_o split-K partials: mid + {0, M*512}
  __bf16* f2o    = attn;           // alias: attn dead after w_o GEMM; slice1 -> projb (dead)

  prep_kernel<<<8960, 256, 0, stream>>>(x, xb, w_q, w_k, w_v, w_o, w_ff1, w_ff2,
                                        wt_qkv, wt_qkv + 512 * 512, wt_qkv + 2 * 512 * 512,
                                        wt_o, wt_ff1, wt_ff2);

  // QKV (fused inverse norms + V-transpose into vtg), grid 128x6=768
  gemm256<4, 6, 1536, 512, 1><<<dim3(768), 512, 0, stream>>>(xb, wt_qkv, qkv, nullptr,
                                                             norms, vtg);
  attn_kernel<<<dim3(1024), 256, 0, stream>>>(qkv, vtg, norms, attn);
  // w_o proj -> two bf16 split-K partials into mid (grid 128x2x2=512)
  gemm256<0, 2, 512, 512, 2><<<dim3(512), 512, 0, stream>>>(attn, wt_o, wo_p, nullptr,
                                                            nullptr, nullptr);
  // LN1: x + wo_a + wo_b -> h1b (bf16)
  resid_ln<false, false, true, true><<<4096, 256, 0, stream>>>(x, nullptr, wo_p,
                                                               wo_p + (size_t)Mrows * 512,
                                                               nullptr, g1, b1, nullptr, h1b);
  // FFN1 (+bias, relu): grid 128x8=1024
  gemm256<2, 8, 2048, 512, 1><<<dim3(1024), 512, 0, stream>>>(h1b, wt_ff1, mid, b_ff1,
                                                              nullptr, nullptr);
  // FFN2 -> two bf16 split-K partials (grid 128x2x2=512)
  gemm256<0, 2, 512, 2048, 2><<<dim3(512), 512, 0, stream>>>(mid, wt_ff2, f2o, nullptr,
                                                             nullptr, nullptr);
  // LN2: h1b + f2o_a + f2o_b + b_ff2 -> out (f32)
  resid_ln<true, true, false, true><<<4096, 256, 0, stream>>>(nullptr, h1b, f2o,
                                                              f2o + (size_t)Mrows * 512,
                                                              b_ff2, g2, b2, out, nullptr);
}

// Round 12
// 299.042 us; speedup vs baseline: 1.0277x; 1.0277x over previous
//
#include <hip/hip_runtime.h>
#include <cmath>

// ---------------------------------------------------------------- types
typedef __bf16 bf16x8 __attribute__((ext_vector_type(8)));
typedef __bf16 bf16x4 __attribute__((ext_vector_type(4)));
typedef float  floatx4 __attribute__((ext_vector_type(4)));

#define LN_EPS 1e-5f
#define INV_TEMP 0.125f   // 1/sqrt(64)

// B=32 S=512 D=512 H=8 DK=DV=64 DFF=2048, M = B*S = 16384
static const int Mrows = 16384;

__device__ __forceinline__ void gload_lds16(const void* g, void* l) {
  __builtin_amdgcn_global_load_lds(
      (const __attribute__((address_space(1))) void*)g,
      (__attribute__((address_space(3))) void*)l, 16, 0, 0);
}

// ---------------------------------------------------------------- fused prep: x->bf16 + 6 weight transposes
__global__ __launch_bounds__(256) void prep_kernel(const float* __restrict__ x, __bf16* __restrict__ xb,
                                                   const float* __restrict__ wq, const float* __restrict__ wk,
                                                   const float* __restrict__ wv, const float* __restrict__ wo,
                                                   const float* __restrict__ wff1, const float* __restrict__ wff2,
                                                   __bf16* __restrict__ tq, __bf16* __restrict__ tk,
                                                   __bf16* __restrict__ tv, __bf16* __restrict__ to_,
                                                   __bf16* __restrict__ tff1, __bf16* __restrict__ tff2) {
  const int bid = blockIdx.x, tid = threadIdx.x;
  if (bid < 8192) {
    int i = bid * 256 + tid;
    float4 v = ((const float4*)x)[i];
    __bf16* d = xb + i * 4;
    d[0] = (__bf16)v.x; d[1] = (__bf16)v.y; d[2] = (__bf16)v.z; d[3] = (__bf16)v.w;
    return;
  }
  __shared__ __bf16 til[64][72];
  int t = bid - 8192;
  const float* src; __bf16* dst; int R, C, bx, by;
  if (t < 256) {
    int w = t >> 6, tt = t & 63;
    const float* srcs[4] = {wq, wk, wv, wo};
    __bf16* dsts[4] = {tq, tk, tv, to_};
    src = srcs[w]; dst = dsts[w]; R = 512; C = 512; bx = tt & 7; by = tt >> 3;
  } else if (t < 512) {
    int tt = t - 256;
    src = wff1; dst = tff1; R = 512; C = 2048; bx = tt & 31; by = tt >> 5;
  } else {
    int tt = t - 512;
    src = wff2; dst = tff2; R = 2048; C = 512; bx = tt & 7; by = tt >> 3;
  }
  const float* s = src + (size_t)(by * 64) * C + bx * 64;
  int r = tid >> 4, c4 = (tid & 15) * 4;
  for (int p = 0; p < 4; ++p) {
    int rr = r + p * 16;
    float4 v = *(const float4*)(s + (size_t)rr * C + c4);
    til[c4 + 0][rr] = (__bf16)v.x;
    til[c4 + 1][rr] = (__bf16)v.y;
    til[c4 + 2][rr] = (__bf16)v.z;
    til[c4 + 3][rr] = (__bf16)v.w;
  }
  __syncthreads();
  __bf16* d = dst + (size_t)(bx * 64) * R + by * 64;
  int orow = tid >> 3, oc8 = (tid & 7) * 8;
  for (int p = 0; p < 2; ++p) {
    int rr = orow + p * 32;
    *(bf16x8*)(d + (size_t)rr * R + oc8) = *(const bf16x8*)(&til[rr][oc8]);
  }
}

// ---------------------------------------------------------------- 128x256 8-wave GEMM, 3-slot K-half ring
// (unchanged from R11 - passing; used for QKV / w_o / FFN2)
template <int EPI, int NBN, int NDIM, int KDIM, int NKS>
__global__ __launch_bounds__(512, 4) void gemm256(const __bf16* __restrict__ A,
                                                  const __bf16* __restrict__ Bt,
                                                  __bf16* __restrict__ Cv,
                                                  const float* __restrict__ bias,
                                                  float* __restrict__ norms,
                                                  __bf16* __restrict__ vtg) {
  __shared__ __align__(16) char smem[73728];
  const int tid = threadIdx.x;
  const int wave = tid >> 6, lane = tid & 63;
  const int l15 = lane & 15, quad = lane >> 4;
  const int wm = wave >> 2, wn = wave & 3;

  constexpr int NBM = Mrows / 128;          // 128
  constexpr int NBLK = NBM * NBN * NKS;
  constexpr int KS = KDIM / NKS;
  constexpr int NTH = KS / 32;

  int id = blockIdx.x;
  int t = (id & 7) * (NBLK >> 3) + (id >> 3);   // XCD-chunked bijective swizzle
  const int ks = t / (NBM * NBN);
  t -= ks * (NBM * NBN);
  const int nblk = t % NBN, mblk = t / NBN;
  const int m0 = mblk * 128, n0 = nblk * 256;
  const __bf16* Ab = A + (size_t)ks * KS;
  const __bf16* Bb = Bt + (size_t)ks * KS;
  __bf16* Cw = Cv + (size_t)ks * Mrows * NDIM;
  (void)bias;

  // stage mapping: 24 chunks (A 0-7, B 8-23), 3 per wave; pair-line layout.
  const int l3 = lane >> 3, s_ = lane & 7;
  const int rl = l3 * 2 + (s_ >> 2);
  const int ksw = (s_ & 3) ^ (l3 & 3);
  const __bf16* sb[3];
  int ldo[3];
#pragma unroll
  for (int j = 0; j < 3; ++j) {
    int c = wave * 3 + j;
    int isB = c >= 8 ? 1 : 0;
    int cc = c - isB * 8;
    int row = cc * 16 + rl;
    sb[j] = (isB ? Bb + (size_t)(n0 + row) * KDIM
                 : Ab + (size_t)(m0 + row) * KDIM) + ksw * 8;
    ldo[j] = isB * 8192 + cc * 1024 + lane * 16;
  }

  const int lrt = (l15 >> 1) * 128 + (((l15 & 1) * 4 + (quad ^ ((l15 >> 1) & 3))) * 16);

  floatx4 zero = {0.f, 0.f, 0.f, 0.f};
  floatx4 acc[4][4];
#pragma unroll
  for (int i = 0; i < 4; ++i)
#pragma unroll
    for (int j = 0; j < 4; ++j) acc[i][j] = zero;

#define STAGEH(h, slotIdx)                                                   \
  {                                                                          \
    _Pragma("unroll") for (int j = 0; j < 3; ++j)                            \
        gload_lds16(sb[j] + (h) * 32, smem + (slotIdx) * 24576 + ldo[j]);    \
  }

#define READMFMA(slotIdx)                                                    \
  {                                                                          \
    const char* slotp = smem + (slotIdx) * 24576;                            \
    bf16x8 aF[4], bF[4];                                                     \
    _Pragma("unroll") for (int i = 0; i < 4; ++i)                            \
      aF[i] = *(const bf16x8*)(slotp + (wm * 4 + i) * 1024 + lrt);           \
    _Pragma("unroll") for (int j = 0; j < 4; ++j)                            \
      bF[j] = *(const bf16x8*)(slotp + 8192 + (wn * 4 + j) * 1024 + lrt);    \
    DOSTAGE_HOOK;                                                            \
    __builtin_amdgcn_s_setprio(1);                                           \
    _Pragma("unroll") for (int i = 0; i < 4; ++i)                            \
      _Pragma("unroll") for (int j = 0; j < 4; ++j)                          \
        acc[i][j] = __builtin_amdgcn_mfma_f32_16x16x32_bf16(aF[i], bF[j],    \
                                                            acc[i][j], 0, 0, 0); \
    __builtin_amdgcn_s_setprio(0);                                           \
  }

  STAGEH(0, 0);
  STAGEH(1, 1);

  int sl = 0;
  for (int h = 0; h < NTH - 1; ++h) {
    asm volatile("s_waitcnt vmcnt(3)" ::: "memory");
    __builtin_amdgcn_s_barrier();
    int st = (sl == 0) ? 2 : sl - 1;          // (sl+2)%3
    if (h < NTH - 2) {
#define DOSTAGE_HOOK STAGEH(h + 2, st)
      READMFMA(sl);
#undef DOSTAGE_HOOK
    } else {
#define DOSTAGE_HOOK
      READMFMA(sl);
#undef DOSTAGE_HOOK
    }
    sl = (sl == 2) ? 0 : sl + 1;
  }
  asm volatile("s_waitcnt vmcnt(0)" ::: "memory");
  __builtin_amdgcn_s_barrier();
#define DOSTAGE_HOOK
  READMFMA(sl);
#undef DOSTAGE_HOOK

#undef STAGEH
#undef READMFMA

  if (EPI == 4) {
    int head_global = (n0 + wn * 64) >> 6;
    int kind = head_global >> 3;
    if (kind < 2) {
      int h = head_global & 7;
#pragma unroll
      for (int ii = 0; ii < 4; ++ii)
#pragma unroll
        for (int r = 0; r < 4; ++r) {
          float sq = 0.f;
#pragma unroll
          for (int jj = 0; jj < 4; ++jj) {
            float v = acc[ii][jj][r];
            sq += v * v;
          }
          for (int m = 1; m < 16; m <<= 1) sq += __shfl_xor(sq, m, 64);
          if (l15 == 0) {
            int arow = m0 + wm * 64 + ii * 16 + quad * 4 + r;
            int bb = arow >> 9, ss = arow & 511;
            norms[kind * 131072 + ((bb << 3) + h) * 512 + ss] = rsqrtf(sq);
          }
        }
    } else {
      const int PADT = 72;
      __bf16* Ct = (__bf16*)smem;
      int bb = m0 >> 9, s0r = m0 & 511;
#pragma unroll
      for (int hh = 0; hh < 2; ++hh) {
        __builtin_amdgcn_s_barrier();
        if (wm == hh) {
#pragma unroll
          for (int ii = 0; ii < 4; ++ii)
#pragma unroll
            for (int jj = 0; jj < 4; ++jj) {
              bf16x4 pk;
#pragma unroll
              for (int r = 0; r < 4; ++r) pk[r] = (__bf16)acc[ii][jj][r];
              *(bf16x4*)(Ct + (wn * 64 + jj * 16 + l15) * PADT + ii * 16 + quad * 4) = pk;
            }
        }
        __builtin_amdgcn_s_barrier();
#pragma unroll
        for (int p = 0; p < 4; ++p) {
          int c = p * 64 + (tid >> 3);
          int s8 = (tid & 7) * 8;
          int h = ((n0 + c) >> 6) & 7, d = c & 63;
          *(bf16x8*)(vtg + ((size_t)(((bb << 3) + h) * 64 + d)) * 512 + s0r + hh * 64 + s8) =
              *(const bf16x8*)(Ct + c * PADT + s8);
        }
      }
      return;
    }
  }

  const int PADC = 264;
  __bf16* Cs = (__bf16*)smem;
  float bv[4];
  if (EPI == 2) {
#pragma unroll
    for (int j = 0; j < 4; ++j) bv[j] = bias[n0 + wn * 64 + j * 16 + l15];
  }
#pragma unroll
  for (int hh = 0; hh < 2; ++hh) {
    __builtin_amdgcn_s_barrier();
    if (wm == hh) {
#pragma unroll
      for (int i = 0; i < 4; ++i)
#pragma unroll
        for (int j = 0; j < 4; ++j)
#pragma unroll
          for (int r = 0; r < 4; ++r) {
            float v = acc[i][j][r];
            if (EPI == 2) {
              v += bv[j];
              v = v > 0.f ? v : 0.f;
            }
            Cs[(i * 16 + quad * 4 + r) * PADC + wn * 64 + j * 16 + l15] = (__bf16)v;
          }
    }
    __builtin_amdgcn_s_barrier();
#pragma unroll
    for (int p = 0; p < 4; ++p) {
      int rowl = p * 16 + (tid >> 5);
      int c8 = (tid & 31) * 8;
      *(bf16x8*)(Cw + (size_t)(m0 + hh * 64 + rowl) * NDIM + n0 + c8) =
          *(const bf16x8*)(Cs + rowl * PADC + c8);
    }
  }
}

// ---------------------------------------------------------------- 256x256 8-wave GEMM, high-intensity wave tile
// NEW (this round): wave owns 128x64 (acc 8x4 = 128 regs) -> LDS intensity
// 42.7 FLOP/B vs 64x64's 32 (the wall capping MfmaUtil at ~40%). 3-slot ring
// of 32KB K=32 slots (96KB, 1 block/CU). Same pair-line conflict-free layout,
// counted vmcnt(4), NO lgkm drain (R11), setprio. This combines all three
// post-R7 fixes with the big tile for the first time. FFN1 only; FFN2 on the
// old kernel is the same-FLOP control.
template <int EPI, int NBN, int NDIM, int KDIM>
__global__ __launch_bounds__(512, 2) void gemmBig(const __bf16* __restrict__ A,
                                                  const __bf16* __restrict__ Bt,
                                                  __bf16* __restrict__ Cv,
                                                  const float* __restrict__ bias) {
  __shared__ __align__(16) char smem[98304];
  const int tid = threadIdx.x;
  const int wave = tid >> 6, lane = tid & 63;
  const int l15 = lane & 15, quad = lane >> 4;
  const int wm = wave >> 2, wn = wave & 3;

  constexpr int NBM = Mrows / 256;          // 64
  constexpr int NBLK = NBM * NBN;           // divisible by 8
  constexpr int NTH = KDIM / 32;

  int id = blockIdx.x;
  int t = (id & 7) * (NBLK >> 3) + (id >> 3);   // XCD-chunked bijective swizzle
  const int nblk = t % NBN, mblk = t / NBN;
  const int m0 = mblk * 256, n0 = nblk * 256;

  // stage mapping: 32 chunks of 1KB (A 0-15 rows c*16, B 16-31), 4 per wave.
  const int l3 = lane >> 3, s_ = lane & 7;
  const int rl = l3 * 2 + (s_ >> 2);
  const int ksw = (s_ & 3) ^ (l3 & 3);
  const __bf16* sb[4];
  int ldo[4];
#pragma unroll
  for (int j = 0; j < 4; ++j) {
    int c = wave * 4 + j;
    int isB = c >= 16 ? 1 : 0;
    int row = (c - isB * 16) * 16 + rl;
    sb[j] = (isB ? Bt + (size_t)(n0 + row) * KDIM
                 : A + (size_t)(m0 + row) * KDIM) + ksw * 8;
    ldo[j] = c * 1024 + lane * 16;
  }

  const int lrt = (l15 >> 1) * 128 + (((l15 & 1) * 4 + (quad ^ ((l15 >> 1) & 3))) * 16);

  floatx4 zero = {0.f, 0.f, 0.f, 0.f};
  floatx4 acc[8][4];
#pragma unroll
  for (int i = 0; i < 8; ++i)
#pragma unroll
    for (int j = 0; j < 4; ++j) acc[i][j] = zero;

#define STAGEB(h, slotIdx)                                                   \
  {                                                                          \
    _Pragma("unroll") for (int j = 0; j < 4; ++j)                            \
        gload_lds16(sb[j] + (h) * 32, smem + (slotIdx) * 32768 + ldo[j]);    \
  }

#define READMFMAB(slotIdx)                                                   \
  {                                                                          \
    const char* slotp = smem + (slotIdx) * 32768;                            \
    bf16x8 aF[8], bF[4];                                                     \
    _Pragma("unroll") for (int j = 0; j < 4; ++j)                            \
      bF[j] = *(const bf16x8*)(slotp + 16384 + (wn * 4 + j) * 1024 + lrt);   \
    _Pragma("unroll") for (int i = 0; i < 8; ++i)                            \
      aF[i] = *(const bf16x8*)(slotp + (wm * 8 + i) * 1024 + lrt);           \
    DOSTAGE_HOOK;                                                            \
    __builtin_amdgcn_s_setprio(1);                                           \
    _Pragma("unroll") for (int i = 0; i < 8; ++i)                            \
      _Pragma("unroll") for (int j = 0; j < 4; ++j)                          \
        acc[i][j] = __builtin_amdgcn_mfma_f32_16x16x32_bf16(aF[i], bF[j],    \
                                                            acc[i][j], 0, 0, 0); \
    __builtin_amdgcn_s_setprio(0);                                           \
  }

  STAGEB(0, 0);
  STAGEB(1, 1);

  int sl = 0;
  for (int h = 0; h < NTH - 1; ++h) {
    asm volatile("s_waitcnt vmcnt(4)" ::: "memory");
    __builtin_amdgcn_s_barrier();
    int st = (sl == 0) ? 2 : sl - 1;          // (sl+2)%3
    if (h < NTH - 2) {
#define DOSTAGE_HOOK STAGEB(h + 2, st)
      READMFMAB(sl);
#undef DOSTAGE_HOOK
    } else {
#define DOSTAGE_HOOK
      READMFMAB(sl);
#undef DOSTAGE_HOOK
    }
    sl = (sl == 2) ? 0 : sl + 1;
  }
  asm volatile("s_waitcnt vmcnt(0)" ::: "memory");
  __builtin_amdgcn_s_barrier();
#define DOSTAGE_HOOK
  READMFMAB(sl);
#undef DOSTAGE_HOOK

#undef STAGEB
#undef READMFMAB

  // epilogue: 128-row halves through LDS (Cs [128][264] = 67.5KB), wide stores
  const int PADC = 264;
  __bf16* Cs = (__bf16*)smem;
  float bv[4];
  if (EPI == 2) {
#pragma unroll
    for (int j = 0; j < 4; ++j) bv[j] = bias[n0 + wn * 64 + j * 16 + l15];
  }
#pragma unroll
  for (int hh = 0; hh < 2; ++hh) {
    __builtin_amdgcn_s_barrier();
    if (wm == hh) {
#pragma unroll
      for (int i = 0; i < 8; ++i)
#pragma unroll
        for (int j = 0; j < 4; ++j)
#pragma unroll
          for (int r = 0; r < 4; ++r) {
            float v = acc[i][j][r];
            if (EPI == 2) {
              v += bv[j];
              v = v > 0.f ? v : 0.f;
            }
            Cs[(i * 16 + quad * 4 + r) * PADC + wn * 64 + j * 16 + l15] = (__bf16)v;
          }
    }
    __builtin_amdgcn_s_barrier();
#pragma unroll
    for (int p = 0; p < 8; ++p) {
      int rowl = p * 16 + (tid >> 5);
      int c8 = (tid & 31) * 8;
      *(bf16x8*)(Cv + (size_t)(m0 + hh * 128 + rowl) * NDIM + n0 + c8) =
          *(const bf16x8*)(Cs + rowl * PADC + c8);
    }
  }
}

// ---------------------------------------------------------------- attention (2-slot K/V ring, hoisted fragments)
// (unchanged from round 10/11 - passing)
__global__ __launch_bounds__(256) void attn_kernel(const __bf16* __restrict__ qkv,
                                                   const __bf16* __restrict__ vtg,
                                                   const float* __restrict__ norms,
                                                   __bf16* __restrict__ out) {
  __shared__ __align__(16) __bf16 KV[2][8192];   // [slot][K 8KB | V 8KB] = 32KB
  __shared__ __align__(16) __bf16 P2[4][16 * 72];
  const int tid = threadIdx.x, wave = tid >> 6, lane = tid & 63;
  const int l15 = lane & 15, quad = lane >> 4;
  const int bh = blockIdx.x & 255;
  const int qq = blockIdx.x >> 8;
  const int b = bh >> 3, h = bh & 7;
  const int qbase = qq * 128 + wave * 32;
  const int rs = lane >> 3;
  const int swz_st = ((lane & 7) ^ rs) * 8;
  const int s7 = l15 & 7;

  const __bf16* Qb = qkv + (size_t)(b * 512) * 1536 + h * 64;
  const __bf16* Kb = Qb + 512;
  const __bf16* Vtb = vtg + (size_t)bh * 32768;
  const float* nkinv = norms + 131072 + bh * 512;
  const float* nqinv = norms + bh * 512;
  __bf16* Pw = P2[wave];

  bf16x8 aq[2][2];
  float cq[2];
  for (int ch = 0; ch < 2; ++ch) {
    int qrow = qbase + ch * 16;
    aq[ch][0] = *(const bf16x8*)(Qb + (size_t)(qrow + l15) * 1536 + quad * 8);
    aq[ch][1] = *(const bf16x8*)(Qb + (size_t)(qrow + l15) * 1536 + 32 + quad * 8);
    cq[ch] = nqinv[qrow + l15] * INV_TEMP;
  }

  floatx4 zero = {0.f, 0.f, 0.f, 0.f};
  floatx4 o[2][4];
  float lsum[2] = {0.f, 0.f};
  for (int ch = 0; ch < 2; ++ch)
    for (int jd = 0; jd < 4; ++jd) o[ch][jd] = zero;

#define STAGEKV(kt, s)                                                        \
  {                                                                           \
    int s0q = (kt) * 64;                                                      \
    _Pragma("unroll") for (int c = 0; c < 4; ++c) {                           \
      int g = wave * 4 + c;                                                   \
      const __bf16* src;                                                      \
      __bf16* dst;                                                            \
      if (g < 8) {                                                            \
        int sk = g * 8 + rs;                                                  \
        src = Kb + (size_t)(s0q + sk) * 1536 + swz_st;                        \
        dst = KV[s] + g * 512;                                                \
      } else {                                                                \
        int g2 = g - 8;                                                       \
        int dd = g2 * 8 + rs;                                                 \
        src = Vtb + (size_t)dd * 512 + s0q + swz_st;                          \
        dst = KV[s] + 4096 + g2 * 512;                                        \
      }                                                                       \
      gload_lds16(src, dst + lane * 8);                                      \
    }                                                                         \
  }

  STAGEKV(0, 0);

  for (int kt = 0; kt < 8; ++kt) {
    int s0 = kt * 64;
    int sl = kt & 1;
    asm volatile("s_waitcnt vmcnt(0)" ::: "memory");
    __builtin_amdgcn_s_barrier();
    if (kt < 7) STAGEKV(kt + 1, sl ^ 1);
    const __bf16* Ks = KV[sl];
    const __bf16* Vs = KV[sl] + 4096;

    floatx4 nk[4];
#pragma unroll
    for (int j = 0; j < 4; ++j)
      nk[j] = *(const floatx4*)(nkinv + s0 + j * 16 + quad * 4);

    bf16x8 kf[4][2];
#pragma unroll
    for (int j = 0; j < 4; ++j) {
      int r64 = (j * 16 + l15) * 64;
      kf[j][0] = *(const bf16x8*)(Ks + r64 + ((quad ^ s7) * 8));
      kf[j][1] = *(const bf16x8*)(Ks + r64 + (((4 + quad) ^ s7) * 8));
    }

    floatx4 z[2][4];
    __builtin_amdgcn_s_setprio(1);
#pragma unroll
    for (int ch = 0; ch < 2; ++ch)
#pragma unroll
      for (int j = 0; j < 4; ++j) {
        floatx4 zz = zero;
        zz = __builtin_amdgcn_mfma_f32_16x16x32_bf16(kf[j][0], aq[ch][0], zz, 0, 0, 0);
        zz = __builtin_amdgcn_mfma_f32_16x16x32_bf16(kf[j][1], aq[ch][1], zz, 0, 0, 0);
        z[ch][j] = zz;
      }
    __builtin_amdgcn_s_setprio(0);

    bf16x8 vf[4][2];
#pragma unroll
    for (int jd = 0; jd < 4; ++jd) {
      int r64 = (jd * 16 + l15) * 64;
      vf[jd][0] = *(const bf16x8*)(Vs + r64 + ((quad ^ s7) * 8));
      vf[jd][1] = *(const bf16x8*)(Vs + r64 + (((4 + quad) ^ s7) * 8));
    }

#pragma unroll
    for (int ch = 0; ch < 2; ++ch) {
#pragma unroll
      for (int j = 0; j < 4; ++j) {
        bf16x4 pk;
#pragma unroll
        for (int r = 0; r < 4; ++r) {
          float p = __expf(z[ch][j][r] * cq[ch] * nk[j][r]);
          lsum[ch] += p;
          pk[r] = (__bf16)p;
        }
        *(bf16x4*)(Pw + l15 * 72 + j * 16 + quad * 4) = pk;
      }
      bf16x8 ap0 = *(const bf16x8*)(Pw + l15 * 72 + quad * 8);
      bf16x8 ap1 = *(const bf16x8*)(Pw + l15 * 72 + 32 + quad * 8);
      __builtin_amdgcn_s_setprio(1);
#pragma unroll
      for (int jd = 0; jd < 4; ++jd) {
        o[ch][jd] = __builtin_amdgcn_mfma_f32_16x16x32_bf16(vf[jd][0], ap0, o[ch][jd], 0, 0, 0);
        o[ch][jd] = __builtin_amdgcn_mfma_f32_16x16x32_bf16(vf[jd][1], ap1, o[ch][jd], 0, 0, 0);
      }
      __builtin_amdgcn_s_setprio(0);
    }
  }
#undef STAGEKV

  for (int ch = 0; ch < 2; ++ch) {
    float s = lsum[ch];
    s += __shfl_xor(s, 16, 64);
    s += __shfl_xor(s, 32, 64);
    float inv = __builtin_amdgcn_rcpf(s);
    int q = qbase + ch * 16 + l15;
    __bf16* op = out + (size_t)(b * 512 + q) * 512 + h * 64;
    for (int jd = 0; jd < 4; ++jd) {
      bf16x4 pk;
      for (int r = 0; r < 4; ++r) pk[r] = (__bf16)(o[ch][jd][r] * inv);
      *(bf16x4*)(op + jd * 16 + quad * 4) = pk;
    }
  }
}

// ---------------------------------------------------------------- residual + layernorm
template <bool X1BF, bool WF, bool WB, bool DUAL>
__global__ __launch_bounds__(256) void resid_ln(const float* __restrict__ X1f,
                                                const __bf16* __restrict__ X1b,
                                                const __bf16* __restrict__ X2,
                                                const __bf16* __restrict__ X2b,
                                                const float* __restrict__ bias,
                                                const float* __restrict__ g,
                                                const float* __restrict__ be,
                                                float* __restrict__ outf,
                                                __bf16* __restrict__ outb) {
  int row = blockIdx.x * 4 + (threadIdx.x >> 6);
  int lane = threadIdx.x & 63;
  float v[8];
  bf16x8 b8 = *(const bf16x8*)(X2 + (size_t)row * 512 + lane * 8);
  if (X1BF) {
    bf16x8 a = *(const bf16x8*)(X1b + (size_t)row * 512 + lane * 8);
    for (int i = 0; i < 8; ++i) v[i] = (float)a[i] + (float)b8[i];
  } else {
    const float4* r1 = (const float4*)(X1f + (size_t)row * 512);
    float4 a0 = r1[lane * 2], a1 = r1[lane * 2 + 1];
    v[0] = a0.x; v[1] = a0.y; v[2] = a0.z; v[3] = a0.w;
    v[4] = a1.x; v[5] = a1.y; v[6] = a1.z; v[7] = a1.w;
    for (int i = 0; i < 8; ++i) v[i] += (float)b8[i];
  }
  if (DUAL) {
    bf16x8 c8 = *(const bf16x8*)(X2b + (size_t)row * 512 + lane * 8);
    for (int i = 0; i < 8; ++i) v[i] += (float)c8[i];
  }
  if (bias) {
    const float* bp = bias + lane * 8;
    for (int i = 0; i < 8; ++i) v[i] += bp[i];
  }
  float s = 0.f, sq = 0.f;
  for (int i = 0; i < 8; ++i) {
    s += v[i];
    sq += v[i] * v[i];
  }
  for (int m = 1; m < 64; m <<= 1) {
    s += __shfl_xor(s, m, 64);
    sq += __shfl_xor(sq, m, 64);
  }
  float mean = s * (1.f / 512.f);
  float var = sq * (1.f / 512.f) - mean * mean;
  float rstd = rsqrtf(var + LN_EPS);
  const float* gp = g + lane * 8;
  const float* bp2 = be + lane * 8;
  float o[8];
  for (int i = 0; i < 8; ++i) o[i] = (v[i] - mean) * rstd * gp[i] + bp2[i];
  if (WF) {
    float4 w0 = {o[0], o[1], o[2], o[3]}, w1 = {o[4], o[5], o[6], o[7]};
    ((float4*)(outf + (size_t)row * 512))[lane * 2] = w0;
    ((float4*)(outf + (size_t)row * 512))[lane * 2 + 1] = w1;
  }
  if (WB) {
    __bf16 tmp[8];
    for (int i = 0; i < 8; ++i) tmp[i] = (__bf16)o[i];
    *(bf16x8*)(outb + (size_t)row * 512 + lane * 8) = *(bf16x8*)tmp;
  }
}

// ---------------------------------------------------------------- launcher
extern "C" void kernel_launch(void* const* d_in, const int* in_sizes, int n_in,
                              void* d_out, int out_size, void* d_ws, size_t ws_size,
                              hipStream_t stream) {
  const float* x     = (const float*)d_in[0];
  const float* w_q   = (const float*)d_in[1];
  const float* w_k   = (const float*)d_in[2];
  const float* w_v   = (const float*)d_in[3];
  const float* w_o   = (const float*)d_in[4];
  const float* w_ff1 = (const float*)d_in[5];
  const float* b_ff1 = (const float*)d_in[6];
  const float* w_ff2 = (const float*)d_in[7];
  const float* b_ff2 = (const float*)d_in[8];
  const float* g1    = (const float*)d_in[9];
  const float* b1    = (const float*)d_in[10];
  const float* g2    = (const float*)d_in[11];
  const float* b2    = (const float*)d_in[12];
  float* out = (float*)d_out;

  char* ws = (char*)d_ws;
  size_t off = 0;
  auto alloc = [&](size_t bytes) -> void* {
    void* p = ws + off;
    off += (bytes + 255) & ~(size_t)255;
    return p;
  };
  __bf16* xb     = (__bf16*)alloc((size_t)Mrows * 512 * 2);
  __bf16* wt_qkv = (__bf16*)alloc((size_t)1536 * 512 * 2);
  __bf16* wt_o   = (__bf16*)alloc((size_t)512 * 512 * 2);
  __bf16* wt_ff1 = (__bf16*)alloc((size_t)2048 * 512 * 2);
  __bf16* wt_ff2 = (__bf16*)alloc((size_t)512 * 2048 * 2);
  __bf16* qkv    = (__bf16*)alloc((size_t)Mrows * 1536 * 2);
  float*  norms  = (float*)alloc((size_t)262144 * 4);
  __bf16* attn   = (__bf16*)alloc((size_t)Mrows * 512 * 2);
  __bf16* projb  = (__bf16*)alloc((size_t)Mrows * 512 * 2);   // contiguous after attn
  __bf16* h1b    = (__bf16*)alloc((size_t)Mrows * 512 * 2);
  __bf16* mid    = (__bf16*)alloc((size_t)Mrows * 2048 * 2);
  __bf16* vtg    = mid;            // alias: vtg dead before w_o writes mid
  __bf16* wo_p   = mid;            // w_o split-K partials: mid + {0, M*512}
  __bf16* f2o    = attn;           // alias: attn dead after w_o GEMM; slice1 -> projb (dead)

  prep_kernel<<<8960, 256, 0, stream>>>(x, xb, w_q, w_k, w_v, w_o, w_ff1, w_ff2,
                                        wt_qkv, wt_qkv + 512 * 512, wt_qkv + 2 * 512 * 512,
                                        wt_o, wt_ff1, wt_ff2);

  // QKV (fused inverse norms + V-transpose into vtg), grid 128x6=768
  gemm256<4, 6, 1536, 512, 1><<<dim3(768), 512, 0, stream>>>(xb, wt_qkv, qkv, nullptr,
                                                             norms, vtg);
  attn_kernel<<<dim3(1024), 256, 0, stream>>>(qkv, vtg, norms, attn);
  // w_o proj -> two bf16 split-K partials into mid (grid 128x2x2=512)
  gemm256<0, 2, 512, 512, 2><<<dim3(512), 512, 0, stream>>>(attn, wt_o, wo_p, nullptr,
                                                            nullptr, nullptr);
  // LN1: x + wo_a + wo_b -> h1b (bf16)
  resid_ln<false, false, true, true><<<4096, 256, 0, stream>>>(x, nullptr, wo_p,
                                                               wo_p + (size_t)Mrows * 512,
                                                               nullptr, g1, b1, nullptr, h1b);
  // FFN1 (+bias, relu): NEW high-intensity 256^2 kernel, grid 64x8=512
  gemmBig<2, 8, 2048, 512><<<dim3(512), 512, 0, stream>>>(h1b, wt_ff1, mid, b_ff1);
  // FFN2 -> two bf16 split-K partials (grid 128x2x2=512) [CONTROL: old kernel]
  gemm256<0, 2, 512, 2048, 2><<<dim3(512), 512, 0, stream>>>(mid, wt_ff2, f2o, nullptr,
                                                             nullptr, nullptr);
  // LN2: h1b + f2o_a + f2o_b + b_ff2 -> out (f32)
  resid_ln<true, true, false, true><<<4096, 256, 0, stream>>>(nullptr, h1b, f2o,
                                                              f2o + (size_t)Mrows * 512,
                                                              b_ff2, g2, b2, out, nullptr);
}